// Round 2
// baseline (1608.342 us; speedup 1.0000x reference)
//
#include <hip/hip_runtime.h>
#include <math.h>

#define B_   64
#define S_   1024
#define DK_  128
#define DV_  128
#define LR_    0.1f
#define THR_   0.1f
#define ITEMP_ 10.0f   // 1/temperature
#define EPS_   1e-6f

struct StepRegs {
  float k[64];   // this thread's 64-col chunk of k for a step
  float ka, kb;  // lane-indexed elements (for ||k||^2 wave-reduce)
  float v;       // v[row]
};

__global__ __launch_bounds__(256, 1)
void sgm_kernel(const float* __restrict__ mem_in,
                const float* __restrict__ key,
                const float* __restrict__ value,
                float* __restrict__ out) {
  const int b    = blockIdx.x;
  const int tid  = threadIdx.x;
  const int r    = tid >> 1;      // output row 0..127
  const int h    = tid & 1;       // column half
  const int col0 = h * 64;
  const int lane = tid & 63;
  const int wv   = tid >> 6;      // wave id 0..3

  // mailbox: [parity][wave] = (seq+1)<<32 | float_bits(partial)
  __shared__ unsigned long long slot[2][4];
  if (tid < 8) slot[tid >> 2][tid & 3] = 0ull;
  __syncthreads();   // once, before the loop — never again

  // ---- memory state into registers (64 floats/thread) ----
  float m[64];
  {
    const float* mp = mem_in + ((size_t)b * DV_ + r) * DK_ + col0;
    #pragma unroll
    for (int i = 0; i < 16; ++i) {
      float4 t = reinterpret_cast<const float4*>(mp)[i];
      m[4*i+0] = t.x; m[4*i+1] = t.y; m[4*i+2] = t.z; m[4*i+3] = t.w;
    }
  }

  const float* kbase = key   + (size_t)b * S_ * DK_;
  const float* vbase = value + (size_t)b * S_ * DV_;
  float*       gout  = out + (size_t)B_ * DV_ * DK_ + (size_t)b * S_;

  auto load_step = [&](int s, StepRegs& R) {
    // scalar loads FIRST so the early ||k|| chain waits only on these
    R.ka = kbase[(size_t)s * DK_ + lane];
    R.kb = kbase[(size_t)s * DK_ + 64 + lane];
    R.v  = vbase[(size_t)s * DV_ + r];
    const float* kp = kbase + (size_t)s * DK_ + col0;
    #pragma unroll
    for (int i = 0; i < 16; ++i) {
      float4 t = reinterpret_cast<const float4*>(kp)[i];
      R.k[4*i+0] = t.x; R.k[4*i+1] = t.y; R.k[4*i+2] = t.z; R.k[4*i+3] = t.w;
    }
  };

  auto knorm = [&](const StepRegs& R) -> float {
    float kk = R.ka * R.ka + R.kb * R.kb;
    #pragma unroll
    for (int mm = 1; mm < 64; mm <<= 1) kk += __shfl_xor(kk, mm, 64);
    return 1.0f / (sqrtf(kk) + EPS_);
  };

  auto compute = [&](int s, const StepRegs& R, float rinorm) {
    // raw dot: mem[r][:] . k[:]  (this thread's 64-col partial)
    float d0 = 0.f, d1 = 0.f, d2 = 0.f, d3 = 0.f;
    #pragma unroll
    for (int i = 0; i < 64; i += 4) {
      d0 = fmaf(m[i+0], R.k[i+0], d0);
      d1 = fmaf(m[i+1], R.k[i+1], d1);
      d2 = fmaf(m[i+2], R.k[i+2], d2);
      d3 = fmaf(m[i+3], R.k[i+3], d3);
    }
    float dpart = (d0 + d1) + (d2 + d3);
    const float d         = dpart + __shfl_xor(dpart, 1, 64); // combine halves
    const float predicted = d * rinorm;
    const float surprise  = predicted - R.v;

    // wave-local sum of surprise^2 (rows pair-duplicated -> 2x)
    float ws = surprise * surprise;
    #pragma unroll
    for (int mm = 1; mm < 64; mm <<= 1) ws += __shfl_xor(ws, mm, 64);

    // ---- barrier-free cross-wave combine via parity-tagged mailbox ----
    const unsigned want = (unsigned)(s + 1);
    volatile unsigned long long* sp = &slot[s & 1][0];
    if (lane == 0)
      sp[wv] = (((unsigned long long)want) << 32) | (unsigned)__float_as_uint(ws);
    const int o0 = (wv + 1) & 3, o1 = (wv + 2) & 3, o2 = (wv + 3) & 3;
    unsigned long long x0, x1, x2;
    do {
      x0 = sp[o0]; x1 = sp[o1]; x2 = sp[o2];
    } while (((unsigned)(x0 >> 32) != want) |
             ((unsigned)(x1 >> 32) != want) |
             ((unsigned)(x2 >> 32) != want));
    float p[4];
    p[wv] = ws;
    p[o0] = __uint_as_float((unsigned)x0);
    p[o1] = __uint_as_float((unsigned)x1);
    p[o2] = __uint_as_float((unsigned)x2);
    const float s2 = 0.5f * ((p[0] + p[1]) + (p[2] + p[3])); // fixed order: bitwise-same gate in all waves

    const float snorm = sqrtf(s2);
    const float gate  = 1.0f / (1.0f + expf(-(snorm - THR_) * ITEMP_));

    // mem -= gate * (pred + lr*surprise) * k_n  ; fold rinorm into scalar
    const float coef = gate * (predicted + LR_ * surprise) * rinorm;
    #pragma unroll
    for (int i = 0; i < 64; ++i) m[i] = fmaf(-coef, R.k[i], m[i]);

    if (tid == 0) gout[s] = gate;
  };

  StepRegs A, Bv;
  load_step(0, A);
  asm volatile("" ::: "memory");
  float rinA = knorm(A), rinB;

  for (int s = 0; s < S_; s += 2) {
    load_step(s + 1, Bv);                       // prefetch; issue pinned here
    asm volatile("" ::: "memory");
    rinB = knorm(Bv);                           // off critical path (next step's norm)
    compute(s, A, rinA);

    const int n2 = (s + 2 < S_) ? (s + 2) : (S_ - 1); // clamp (discarded)
    load_step(n2, A);
    asm volatile("" ::: "memory");
    rinA = knorm(A);
    compute(s + 1, Bv, rinB);
  }

  // ---- write final memory ----
  float* op = out + ((size_t)b * DV_ + r) * DK_ + col0;
  #pragma unroll
  for (int i = 0; i < 16; ++i) {
    float4 t = make_float4(m[4*i+0], m[4*i+1], m[4*i+2], m[4*i+3]);
    reinterpret_cast<float4*>(op)[i] = t;
  }
}

extern "C" void kernel_launch(void* const* d_in, const int* in_sizes, int n_in,
                              void* d_out, int out_size, void* d_ws, size_t ws_size,
                              hipStream_t stream) {
  const float* mem = (const float*)d_in[0];
  const float* key = (const float*)d_in[1];
  const float* val = (const float*)d_in[2];
  float* out = (float*)d_out;
  sgm_kernel<<<B_, 256, 0, stream>>>(mem, key, val, out);
}

// Round 7
// 1595.305 us; speedup vs baseline: 1.0082x; 1.0082x over previous
//
#include <hip/hip_runtime.h>
#include <math.h>

#define B_   64
#define S_   1024
#define DK_  128
#define DV_  128
#define LR_    0.1f
#define THR_   0.1f
#define ITEMP_ 10.0f   // 1/temperature
#define EPS_   1e-6f

// ---- DPP helpers: full-wave64 sum in ~6 VALU ops (no LDS-routed shuffles) ----
template<int CTRL>
__device__ __forceinline__ float dpp_add(float x) {
  int t = __builtin_amdgcn_update_dpp(0, __float_as_int(x), CTRL, 0xf, 0xf, true);
  return x + __int_as_float(t);
}
__device__ __forceinline__ float wave_sum64(float x) {
  x = dpp_add<0x111>(x); // row_shr:1
  x = dpp_add<0x112>(x); // row_shr:2
  x = dpp_add<0x114>(x); // row_shr:4
  x = dpp_add<0x118>(x); // row_shr:8
  x = dpp_add<0x142>(x); // row_bcast:15
  x = dpp_add<0x143>(x); // row_bcast:31  -> total in lane 63
  return __int_as_float(__builtin_amdgcn_readlane(__float_as_int(x), 63));
}
__device__ __forceinline__ float quad_xor1(float x) { // pair-swap lanes 0<->1, 2<->3
  int t = __builtin_amdgcn_update_dpp(0, __float_as_int(x), 0xB1, 0xf, 0xf, true);
  return __int_as_float(t);
}

__global__ __launch_bounds__(256, 1)
void sgm_kernel(const float* __restrict__ mem_in,
                const float* __restrict__ key,
                const float* __restrict__ value,
                float* __restrict__ out) {
  const int b    = blockIdx.x;
  const int tid  = threadIdx.x;
  const int r    = tid >> 1;      // output row 0..127
  const int col0 = (tid & 1) * 64;
  const int lane = tid & 63;
  const int wv   = tid >> 6;

  __shared__ float4 red[2];       // per-parity 4 wave partials

  // ---- memory state into registers ----
  float m[64];
  {
    const float* mp = mem_in + ((size_t)b * DV_ + r) * DK_ + col0;
    #pragma unroll
    for (int i = 0; i < 16; ++i) {
      float4 t = reinterpret_cast<const float4*>(mp)[i];
      m[4*i+0]=t.x; m[4*i+1]=t.y; m[4*i+2]=t.z; m[4*i+3]=t.w;
    }
  }

  const float* kbase = key   + (size_t)b * S_ * DK_;
  const float* vbase = value + (size_t)b * S_ * DV_;
  float*       gout  = out + (size_t)B_ * DV_ * DK_ + (size_t)b * S_;

  float kA[64], kB[64];
  float kaA, kbA, vA, kaB, kbB, vB;
  float c1 = 0.f, u1 = 0.f;   // lagged gate state: c1 = g_{s-1}*rin_{s-1}, u1 = u_{s-1}[r]

  // prologue: k_0 -> A ; B := 0 (acts as k_{-1})
  #pragma unroll
  for (int i = 0; i < 64; ++i) kB[i] = 0.f;
  kaB = 0.f; kbB = 0.f; vB = 0.f;
  {
    kaA = kbase[lane]; kbA = kbase[64 + lane]; vA = vbase[r];
    const float* kp = kbase + col0;
    #pragma unroll
    for (int i = 0; i < 16; ++i) {
      float4 t = reinterpret_cast<const float4*>(kp)[i];
      kA[4*i+0]=t.x; kA[4*i+1]=t.y; kA[4*i+2]=t.z; kA[4*i+3]=t.w;
    }
  }
  asm volatile("" ::: "memory");

  // One pipelined step. Entry: m = M_{s-2}; kC=k_s (cur), kO=k_{s-1} (prev).
  // Exit: m = M_{s-1} (lagged update applied), k_{s+1} prefetched into O.
  auto half = [&](int s, float (&kC)[64], float (&kO)[64],
                  float& kaC, float& kbC, float& vC,
                  float& kaO, float& kbO, float& vO) {
    // wave-uniform scalars for this step (inputs loaded a full step ago)
    const float rinC = 1.0f / (sqrtf(wave_sum64(kaC*kaC + kbC*kbC)) + EPS_);
    const float dkOC = wave_sum64(kaO*kaC + kbO*kbC);   // raw k_{s-1}.k_s

    // matvec on stale m (= M_{s-2}) with raw k_s
    float d0=0.f, d1=0.f, d2=0.f, d3=0.f;
    #pragma unroll
    for (int i = 0; i < 64; i += 4) {
      d0 = fmaf(m[i+0], kC[i+0], d0);
      d1 = fmaf(m[i+1], kC[i+1], d1);
      d2 = fmaf(m[i+2], kC[i+2], d2);
      d3 = fmaf(m[i+3], kC[i+3], d3);
    }
    float part = (d0 + d1) + (d2 + d3);
    const float rawf = part + quad_xor1(part);

    // gate chain: pred = rinC*(raw - c1*dkOC*u1)   [delta-rule correction]
    const float cd    = c1 * dkOC;
    const float pred  = rinC * fmaf(-cd, u1, rawf);
    const float surp  = pred - vC;
    const float usnew = fmaf(LR_, surp, pred);
    const float tot   = wave_sum64(surp * surp);

    if (lane == 0) ((float*)&red[s & 1])[wv] = tot;
    asm volatile("s_waitcnt lgkmcnt(0)" ::: "memory");  // LDS write visible
    __builtin_amdgcn_s_barrier();                       // raw barrier: vmcnt stays in flight
    asm volatile("" ::: "memory");
    const float4 q  = red[s & 1];
    const float s2  = 0.5f * ((q.x + q.y) + (q.z + q.w)); // same order in all waves
    const float g   = 1.0f / (1.0f + __expf((THR_ - sqrtf(s2)) * ITEMP_));
    if (tid == 0) gout[s] = g;

    // lagged rank-1 update for step s-1 (entry c1,u1; kO still = k_{s-1})
    const float a1 = c1 * u1;
    #pragma unroll
    for (int i = 0; i < 64; ++i) m[i] = fmaf(-a1, kO[i], m[i]);

    // prefetch step s+1 into O (after update consumed kO)
    const int sn = (s + 1 < S_) ? (s + 1) : (S_ - 1);
    {
      const float* kp = kbase + (size_t)sn * DK_;
      kaO = kp[lane]; kbO = kp[64 + lane]; vO = vbase[(size_t)sn * DV_ + r];
      const float* kpc = kp + col0;
      #pragma unroll
      for (int i = 0; i < 16; ++i) {
        float4 t = reinterpret_cast<const float4*>(kpc)[i];
        kO[4*i+0]=t.x; kO[4*i+1]=t.y; kO[4*i+2]=t.z; kO[4*i+3]=t.w;
      }
    }
    asm volatile("" ::: "memory");   // pin load issue here

    // rotate lagged gate state
    c1 = g * rinC;
    u1 = usnew;
  };

  for (int s = 0; s < S_; s += 2) {
    half(s,     kA, kB, kaA, kbA, vA, kaB, kbB, vB);
    half(s + 1, kB, kA, kaB, kbB, vB, kaA, kbA, vA);
  }

  // final lagged update for step S-1 (k_{1023} lives in kB)
  {
    const float a1 = c1 * u1;
    #pragma unroll
    for (int i = 0; i < 64; ++i) m[i] = fmaf(-a1, kB[i], m[i]);
  }

  float* op = out + ((size_t)b * DV_ + r) * DK_ + col0;
  #pragma unroll
  for (int i = 0; i < 16; ++i) {
    float4 t = make_float4(m[4*i+0], m[4*i+1], m[4*i+2], m[4*i+3]);
    reinterpret_cast<float4*>(op)[i] = t;
  }
}

extern "C" void kernel_launch(void* const* d_in, const int* in_sizes, int n_in,
                              void* d_out, int out_size, void* d_ws, size_t ws_size,
                              hipStream_t stream) {
  const float* mem = (const float*)d_in[0];
  const float* key = (const float*)d_in[1];
  const float* val = (const float*)d_in[2];
  float* out = (float*)d_out;
  sgm_kernel<<<B_, 256, 0, stream>>>(mem, key, val, out);
}